// Round 5
// baseline (1061.151 us; speedup 1.0000x reference)
//
#include <hip/hip_runtime.h>

#define N_   64
#define C4_  64
#define V_   25
#define T_   128

// ---- fused: (x_b + z_{b-1}) -> depthwise 5-tap conv -> LDS tile ->
//      per-node 1x1 (192 o) -> adjacency -> BN -> LeakyReLU -> out
// Block: 256 thr / 4 waves; wave owns 2 output channels; lane owns a t-pair.
// Staging: thread (cl=tid>>3, seg=tid&7) computes s[cl, seg*16..+15] for one
// (w, cin-half) phase from x/out rows (reg-staged, issued one phase early).
// LDS tile stride 132 floats -> conflict-free b128 writes, 2-way-free b64 reads.
// Grid 512 = 8 XCD * 8 n * 8 cg, XCD-bijective: batch n lives on XCD n%8.
__global__ __launch_bounds__(256, 2)
void k23f(const float* __restrict__ x, const float* __restrict__ gW,
          const float* __restrict__ A,
          const float* __restrict__ conv_w, const float* __restrict__ conv_b,
          const float* __restrict__ bng, const float* __restrict__ bnb,
          const float* __restrict__ bnm, const float* __restrict__ bnv,
          float* __restrict__ out, int branch) {
    __shared__ float Bs0[32 * 132];
    __shared__ float Bs1[32 * 132];
    __shared__ float A_lds[76 * 26];

    int tid  = threadIdx.x;
    int bid  = blockIdx.x;
    int e    = bid & 7;                 // XCD
    int slot = bid >> 3;                // 0..63
    int n    = e + 8 * (slot >> 3);     // 8 n per XCD
    int cg   = slot & 7;                // 8 channel-groups of 8
    int wave = tid >> 6, lane = tid & 63;
    int c0   = __builtin_amdgcn_readfirstlane(cg * 8 + wave * 2);
    int t0   = lane * 2;
    int cl   = tid >> 3, seg = tid & 7; // staging unit

    // stage A once: row = k*25+w, padded stride 26
    for (int i = tid; i < 1950; i += 256) {
        int row = i / 26, col = i - row * 26;
        A_lds[i] = (col < 25) ? A[row * 25 + col] : 0.f;
    }

    // conv taps for this thread's two staging channels (h=0: cl, h=1: 32+cl)
    const float* wpa = conv_w + (branch * C4_ + cl) * 5;
    const float* wpb = conv_w + (branch * C4_ + 32 + cl) * 5;
    float wa0 = wpa[0], wa1 = wpa[1], wa2 = wpa[2], wa3 = wpa[3], wa4 = wpa[4];
    float ba  = conv_b[branch * C4_ + cl];
    float wb0 = wpb[0], wb1 = wpb[1], wb2 = wpb[2], wb3 = wpb[3], wb4 = wpb[4];
    float bb  = conv_b[branch * C4_ + 32 + cl];

    // pending staged loads (x and prev-out)
    float4 pm0, pm1, pm2, pm3; float2 pl, pr;
    float4 qm0, qm1, qm2, qm3; float2 ql, qr;

    auto issue = [&](int w_, int h_) {
        const float* xr = x + ((size_t)(n * 256 + branch * C4_ + h_ * 32 + cl) * V_ + w_) * T_ + seg * 16;
        float2 z2; z2.x = 0.f; z2.y = 0.f;
        pm0 = *(const float4*)(xr);
        pm1 = *(const float4*)(xr + 4);
        pm2 = *(const float4*)(xr + 8);
        pm3 = *(const float4*)(xr + 12);
        pl = seg       ? *(const float2*)(xr - 2)  : z2;
        pr = (seg < 7) ? *(const float2*)(xr + 16) : z2;
        if (branch > 0) {
            const float* zr = out + ((size_t)(n * 256 + (branch - 1) * C4_ + h_ * 32 + cl) * V_ + w_) * T_ + seg * 16;
            qm0 = *(const float4*)(zr);
            qm1 = *(const float4*)(zr + 4);
            qm2 = *(const float4*)(zr + 8);
            qm3 = *(const float4*)(zr + 12);
            ql = seg       ? *(const float2*)(zr - 2)  : z2;
            qr = (seg < 7) ? *(const float2*)(zr + 16) : z2;
        }
    };

    auto convwrite = [&](float t0_, float t1_, float t2_, float t3_, float t4_,
                         float bt, float* dst) {
        float ev[20];
        ev[0] = pl.x;  ev[1] = pl.y;
        ev[2] = pm0.x; ev[3] = pm0.y; ev[4]  = pm0.z; ev[5]  = pm0.w;
        ev[6] = pm1.x; ev[7] = pm1.y; ev[8]  = pm1.z; ev[9]  = pm1.w;
        ev[10]= pm2.x; ev[11]= pm2.y; ev[12] = pm2.z; ev[13] = pm2.w;
        ev[14]= pm3.x; ev[15]= pm3.y; ev[16] = pm3.z; ev[17] = pm3.w;
        ev[18]= pr.x;  ev[19]= pr.y;
        if (branch > 0) {
            ev[0] += ql.x;  ev[1] += ql.y;
            ev[2] += qm0.x; ev[3] += qm0.y; ev[4]  += qm0.z; ev[5]  += qm0.w;
            ev[6] += qm1.x; ev[7] += qm1.y; ev[8]  += qm1.z; ev[9]  += qm1.w;
            ev[10]+= qm2.x; ev[11]+= qm2.y; ev[12] += qm2.z; ev[13] += qm2.w;
            ev[14]+= qm3.x; ev[15]+= qm3.y; ev[16] += qm3.z; ev[17] += qm3.w;
            ev[18]+= qr.x;  ev[19]+= qr.y;
        }
        float* d = dst + cl * 132 + seg * 16;
        #pragma unroll
        for (int i = 0; i < 16; i += 4) {
            float4 o;
            o.x = bt + t0_*ev[i]   + t1_*ev[i+1] + t2_*ev[i+2] + t3_*ev[i+3] + t4_*ev[i+4];
            o.y = bt + t0_*ev[i+1] + t1_*ev[i+2] + t2_*ev[i+3] + t3_*ev[i+4] + t4_*ev[i+5];
            o.z = bt + t0_*ev[i+2] + t1_*ev[i+3] + t2_*ev[i+4] + t3_*ev[i+5] + t4_*ev[i+6];
            o.w = bt + t0_*ev[i+3] + t1_*ev[i+4] + t2_*ev[i+5] + t3_*ev[i+6] + t4_*ev[i+7];
            *(float4*)(d + i) = o;
        }
    };

    float2 y00, y10, y20, y01, y11, y21;
    float2 acc0[V_], acc1[V_];
    #pragma unroll
    for (int v = 0; v < V_; ++v) {
        acc0[v].x = 0.f; acc0[v].y = 0.f;
        acc1[v].x = 0.f; acc1[v].y = 0.f;
    }

    auto mm = [&](const float* Bs, int w_, int h_) {
        const float* bp = Bs + t0;
        const float* Wp = gW + (((size_t)branch * V_ + w_) * 192 + c0 * 3) * C4_ + h_ * 32;
        #pragma unroll 8
        for (int ci = 0; ci < 32; ++ci) {
            float2 sv = *(const float2*)(bp + ci * 132);
            float u0 = Wp[ci],        u1 = Wp[64 + ci],  u2 = Wp[128 + ci];
            float u3 = Wp[192 + ci],  u4 = Wp[256 + ci], u5 = Wp[320 + ci];
            y00.x += u0 * sv.x; y00.y += u0 * sv.y;
            y10.x += u1 * sv.x; y10.y += u1 * sv.y;
            y20.x += u2 * sv.x; y20.y += u2 * sv.y;
            y01.x += u3 * sv.x; y01.y += u3 * sv.y;
            y11.x += u4 * sv.x; y11.y += u4 * sv.y;
            y21.x += u5 * sv.x; y21.y += u5 * sv.y;
        }
    };

    auto astep = [&](int w_) {
        const float* A0 = A_lds + w_ * 26;
        const float* A1 = A_lds + (25 + w_) * 26;
        const float* A2 = A_lds + (50 + w_) * 26;
        #pragma unroll
        for (int vq = 0; vq < 12; ++vq) {
            float2 a0 = *(const float2*)(A0 + 2 * vq);
            float2 a1 = *(const float2*)(A1 + 2 * vq);
            float2 a2 = *(const float2*)(A2 + 2 * vq);
            acc0[2*vq].x   += a0.x*y00.x + a1.x*y10.x + a2.x*y20.x;
            acc0[2*vq].y   += a0.x*y00.y + a1.x*y10.y + a2.x*y20.y;
            acc0[2*vq+1].x += a0.y*y00.x + a1.y*y10.x + a2.y*y20.x;
            acc0[2*vq+1].y += a0.y*y00.y + a1.y*y10.y + a2.y*y20.y;
            acc1[2*vq].x   += a0.x*y01.x + a1.x*y11.x + a2.x*y21.x;
            acc1[2*vq].y   += a0.x*y01.y + a1.x*y11.y + a2.x*y21.y;
            acc1[2*vq+1].x += a0.y*y01.x + a1.y*y11.x + a2.y*y21.x;
            acc1[2*vq+1].y += a0.y*y01.y + a1.y*y11.y + a2.y*y21.y;
        }
        float a0t = A0[24], a1t = A1[24], a2t = A2[24];
        acc0[24].x += a0t*y00.x + a1t*y10.x + a2t*y20.x;
        acc0[24].y += a0t*y00.y + a1t*y10.y + a2t*y20.y;
        acc1[24].x += a0t*y01.x + a1t*y11.x + a2t*y21.x;
        acc1[24].y += a0t*y01.y + a1t*y11.y + a2t*y21.y;
    };

    // prologue: stage phase (0,0) into Bs0
    issue(0, 0);
    convwrite(wa0, wa1, wa2, wa3, wa4, ba, Bs0);
    __syncthreads();

    for (int w = 0; w < V_; ++w) {
        // ---- phase (w,0): Bs0 ready; prefetch (w,1)
        issue(w, 1);
        y00.x=y00.y=y10.x=y10.y=y20.x=y20.y=0.f;
        y01.x=y01.y=y11.x=y11.y=y21.x=y21.y=0.f;
        mm(Bs0, w, 0);
        convwrite(wb0, wb1, wb2, wb3, wb4, bb, Bs1);
        __syncthreads();
        // ---- phase (w,1): Bs1 ready; prefetch (w+1,0)
        if (w < V_ - 1) issue(w + 1, 0);
        mm(Bs1, w, 1);
        astep(w);
        if (w < V_ - 1) convwrite(wa0, wa1, wa2, wa3, wa4, ba, Bs0);
        __syncthreads();
    }

    // epilogue: BN + LeakyReLU + store 2 channels
    float g0 = bng[branch * C4_ + c0],     be0 = bnb[branch * C4_ + c0];
    float mu0 = bnm[branch * C4_ + c0],    va0 = bnv[branch * C4_ + c0];
    float g1 = bng[branch * C4_ + c0 + 1], be1 = bnb[branch * C4_ + c0 + 1];
    float mu1 = bnm[branch * C4_ + c0 + 1],va1 = bnv[branch * C4_ + c0 + 1];
    float sc0 = g0 * rsqrtf(va0 + 1e-5f);
    float sc1 = g1 * rsqrtf(va1 + 1e-5f);
    float* op0 = out + ((size_t)(n * 256 + branch * C4_ + c0) * V_) * T_ + t0;
    float* op1 = op0 + (size_t)V_ * T_;
    #pragma unroll
    for (int v = 0; v < V_; ++v) {
        float zx = (acc0[v].x - mu0) * sc0 + be0;
        float zy = (acc0[v].y - mu0) * sc0 + be0;
        zx = zx > 0.f ? zx : 0.2f * zx;
        zy = zy > 0.f ? zy : 0.2f * zy;
        float2 o2; o2.x = zx; o2.y = zy;
        *(float2*)(op0 + (size_t)v * T_) = o2;
        zx = (acc1[v].x - mu1) * sc1 + be1;
        zy = (acc1[v].y - mu1) * sc1 + be1;
        zx = zx > 0.f ? zx : 0.2f * zx;
        zy = zy > 0.f ? zy : 0.2f * zy;
        o2.x = zx; o2.y = zy;
        *(float2*)(op1 + (size_t)v * T_) = o2;
    }
}

// ---------------- K4: passthrough split[3] -> out channels 192..255 ---------
__global__ __launch_bounds__(256)
void k4_copy(const float* __restrict__ x, float* __restrict__ out) {
    int i = blockIdx.x * blockDim.x + threadIdx.x;   // 0 .. 3,276,799
    int n = i / 51200;
    int j = i % 51200;
    const float4* src = (const float4*)(x + (size_t)(n * 256 + 192) * (V_ * T_));
    float4* dst = (float4*)(out + (size_t)(n * 256 + 192) * (V_ * T_));
    dst[j] = src[j];
}

extern "C" void kernel_launch(void* const* d_in, const int* in_sizes, int n_in,
                              void* d_out, int out_size, void* d_ws, size_t ws_size,
                              hipStream_t stream) {
    const float* x      = (const float*)d_in[0];
    const float* A      = (const float*)d_in[1];
    const float* conv_w = (const float*)d_in[2];
    const float* conv_b = (const float*)d_in[3];
    const float* gW     = (const float*)d_in[4];
    const float* bng    = (const float*)d_in[5];
    const float* bnb    = (const float*)d_in[6];
    const float* bnm    = (const float*)d_in[7];
    const float* bnv    = (const float*)d_in[8];
    float* out = (float*)d_out;

    for (int i = 0; i < 3; ++i) {
        hipLaunchKernelGGL(k23f, dim3(512), dim3(256), 0, stream,
                           x, gW, A, conv_w, conv_b, bng, bnb, bnm, bnv, out, i);
    }
    hipLaunchKernelGGL(k4_copy, dim3(12800), dim3(256), 0, stream, x, out);
}